// Round 1
// baseline (879.882 us; speedup 1.0000x reference)
//
#include <hip/hip_runtime.h>
#include <hip/hip_bf16.h>
#include <math.h>

// Problem constants (from reference)
#define FEAT 128
#define HID 64
#define LAT 32
#define NG 64
#define MAXN 30
// out layout: adj (30*30=900) | mu (64*32=2048) | logvar (2048)

__global__ void k_init_deg(float* deg, int N) {
    int i = blockIdx.x * blockDim.x + threadIdx.x;
    if (i < N) deg[i] = 1.0f;
}

__global__ void k_edge_deg(const int* dst, float* deg, int E) {
    int i = blockIdx.x * blockDim.x + threadIdx.x;
    if (i < E) atomicAdd(&deg[dst[i]], 1.0f);
}

__global__ void k_dinv(float* deg, int N) {
    int i = blockIdx.x * blockDim.x + threadIdx.x;
    if (i < N) deg[i] = rsqrtf(deg[i]);  // in-place: deg -> dinv
}

__global__ void k_zero(float* p, int n) {
    int i = blockIdx.x * blockDim.x + threadIdx.x;
    if (i < n) p[i] = 0.0f;
}

// Fused GEMM: hw = in @ W  (N x K @ K x 64), and agg-init = hw*snorm + b.
// One wave per row; W staged in LDS. agg may alias `in` (row read completes
// before row write via data dependency).
template <int K>
__global__ __launch_bounds__(256) void k_gemm(const float* __restrict__ in,
                                              const float* __restrict__ W,
                                              const float* __restrict__ b,
                                              const float* __restrict__ dinv,
                                              float* __restrict__ hw,
                                              float* __restrict__ agg,
                                              int N) {
    __shared__ float Wl[K * 64];
    __shared__ float xr[4][K];
    int tid = threadIdx.x;
    for (int i = tid; i < K * 64; i += 256) Wl[i] = W[i];
    __syncthreads();
    int lane = tid & 63;
    int wv = tid >> 6;
    float bias = b[lane];
    int stride = gridDim.x * 4;
    for (int row = blockIdx.x * 4 + wv; row < N; row += stride) {
        for (int k = lane; k < K; k += 64) xr[wv][k] = in[(long)row * K + k];
        float acc = 0.0f;
#pragma unroll
        for (int k = 0; k < K; ++k) acc += xr[wv][k] * Wl[k * 64 + lane];
        float di = dinv[row];
        hw[(long)row * 64 + lane] = acc;
        agg[(long)row * 64 + lane] = acc * (di * di) + bias;
    }
}

// One wave per edge: agg[dst] += hw[src] * dinv[src]*dinv[dst]
__global__ __launch_bounds__(256) void k_scatter(const int* __restrict__ src,
                                                 const int* __restrict__ dst,
                                                 const float* __restrict__ dinv,
                                                 const float* __restrict__ hw,
                                                 float* __restrict__ agg,
                                                 int E) {
    int wid = (blockIdx.x * blockDim.x + threadIdx.x) >> 6;
    int lane = threadIdx.x & 63;
    int nw = (gridDim.x * blockDim.x) >> 6;
    for (int e = wid; e < E; e += nw) {
        int s = src[e], d = dst[e];
        float en = dinv[s] * dinv[d];
        float v = hw[(long)s * 64 + lane] * en;
        atomicAdd(&agg[(long)d * 64 + lane], v);
    }
}

__global__ void k_relu(float* p, long n) {
    long i = (long)blockIdx.x * blockDim.x + threadIdx.x;
    long stride = (long)gridDim.x * blockDim.x;
    for (; i < n; i += stride) p[i] = fmaxf(p[i], 0.0f);
}

// relu of agg2 fused with mean-pool accumulation (one wave per node)
__global__ __launch_bounds__(256) void k_relu_pool(const float* __restrict__ agg,
                                                   const int* __restrict__ batch,
                                                   float* __restrict__ pooled,
                                                   float* __restrict__ counts,
                                                   int N) {
    int wid = (blockIdx.x * blockDim.x + threadIdx.x) >> 6;
    int lane = threadIdx.x & 63;
    int nw = (gridDim.x * blockDim.x) >> 6;
    for (int i = wid; i < N; i += nw) {
        int g = batch[i];
        float v = fmaxf(agg[(long)i * 64 + lane], 0.0f);
        atomicAdd(&pooled[g * 64 + lane], v);
        if (lane == 0) atomicAdd(&counts[g], 1.0f);
    }
}

__global__ void k_pool_div(float* pooled, const float* counts) {
    int i = blockIdx.x * blockDim.x + threadIdx.x;  // 4096 threads
    if (i < NG * HID) {
        float c = fmaxf(counts[i >> 6], 1.0f);
        pooled[i] /= c;
    }
}

// mu / logvar heads -> out[900 + idx]
__global__ void k_heads(const float* __restrict__ pooled,
                        const float* __restrict__ Wmu, const float* __restrict__ bmu,
                        const float* __restrict__ Wlv, const float* __restrict__ blv,
                        float* __restrict__ out) {
    int idx = blockIdx.x * blockDim.x + threadIdx.x;
    if (idx >= 2 * NG * LAT) return;
    int which = idx >> 11;          // 0: mu, 1: logvar
    int r = idx & (NG * LAT - 1);
    int g = r >> 5, l = r & 31;
    const float* W = which ? Wlv : Wmu;
    const float* b = which ? blv : bmu;
    float s = b[l];
#pragma unroll 8
    for (int h = 0; h < HID; ++h) s += pooled[g * 64 + h] * W[h * 32 + l];
    out[900 + idx] = s;
}

// Single-block decoder: z0 -> hrow -> emb(30x64) -> hi/hj -> adj
__global__ __launch_bounds__(256) void k_decoder(const float* __restrict__ Wl1,
                                                 const float* __restrict__ bl1,
                                                 const float* __restrict__ Wl2,
                                                 const float* __restrict__ bl2,
                                                 const float* __restrict__ We1,
                                                 const float* __restrict__ be1,
                                                 const float* __restrict__ We2,
                                                 const float* __restrict__ be2,
                                                 float* __restrict__ out) {
    __shared__ float z0[LAT];
    __shared__ float hr[HID];
    __shared__ float emb[MAXN * HID];
    __shared__ float hi[MAXN * HID];
    __shared__ float hj[MAXN * HID];
    __shared__ float sbe1[HID];
    __shared__ float sWe2[HID];
    int tid = threadIdx.x;
    if (tid < LAT) z0[tid] = out[900 + tid];  // mu row of graph 0
    if (tid < HID) { sbe1[tid] = be1[tid]; sWe2[tid] = We2[tid]; }
    __syncthreads();
    if (tid < HID) {
        float s = bl1[tid];
#pragma unroll
        for (int l = 0; l < LAT; ++l) s += z0[l] * Wl1[l * HID + tid];
        hr[tid] = fmaxf(s, 0.0f);
    }
    __syncthreads();
    for (int i = tid; i < MAXN * HID; i += 256) {
        float s = bl2[i];
#pragma unroll 8
        for (int h = 0; h < HID; ++h) s += hr[h] * Wl2[h * (HID * MAXN) + i];
        emb[i] = s;
    }
    __syncthreads();
    for (int i = tid; i < MAXN * HID; i += 256) {
        int n = i >> 6, k = i & 63;
        float a = 0.0f, bb = 0.0f;
#pragma unroll 8
        for (int f = 0; f < HID; ++f) {
            float e = emb[n * 64 + f];
            a += e * We1[f * 64 + k];
            bb += e * We1[(64 + f) * 64 + k];
        }
        hi[i] = a;
        hj[i] = bb;
    }
    __syncthreads();
    float bias2 = be2[0];
    for (int idx = tid; idx < MAXN * MAXN; idx += 256) {
        int i = idx / MAXN, j = idx % MAXN;
        if (i == j) { out[idx] = 0.0f; continue; }
        int a = i < j ? i : j;
        int b = i < j ? j : i;
        float s = bias2;
#pragma unroll 8
        for (int k = 0; k < HID; ++k)
            s += fmaxf(hi[a * 64 + k] + hj[b * 64 + k] + sbe1[k], 0.0f) * sWe2[k];
        out[idx] = 1.0f / (1.0f + expf(-s));
    }
}

extern "C" void kernel_launch(void* const* d_in, const int* in_sizes, int n_in,
                              void* d_out, int out_size, void* d_ws, size_t ws_size,
                              hipStream_t stream) {
    const float* x = (const float*)d_in[0];
    const int* ei = (const int*)d_in[1];
    const int* batch = (const int*)d_in[2];
    // d_in[3] = num_nodes (==30, fixed by out_size)
    const float* W1 = (const float*)d_in[4];
    const float* b1 = (const float*)d_in[5];
    const float* W2 = (const float*)d_in[6];
    const float* b2 = (const float*)d_in[7];
    const float* Wmu = (const float*)d_in[8];
    const float* bmu = (const float*)d_in[9];
    const float* Wlv = (const float*)d_in[10];
    const float* blv = (const float*)d_in[11];
    const float* Wl1 = (const float*)d_in[12];
    const float* bl1 = (const float*)d_in[13];
    const float* Wl2 = (const float*)d_in[14];
    const float* bl2 = (const float*)d_in[15];
    const float* We1 = (const float*)d_in[16];
    const float* be1 = (const float*)d_in[17];
    const float* We2 = (const float*)d_in[18];
    const float* be2 = (const float*)d_in[19];

    const int N = in_sizes[2];            // 50000
    const int E = in_sizes[1] / 2;        // 800000
    const int* src = ei;
    const int* dst = ei + E;

    // workspace carve-up (all f32), 256B aligned
    char* ws = (char*)d_ws;
    size_t off = 0;
    auto alloc = [&](size_t nfloats) {
        float* p = (float*)(ws + off);
        off = (off + nfloats * 4 + 255) & ~(size_t)255;
        return p;
    };
    float* dinv = alloc(N);              // deg -> dinv in place
    float* bufA = alloc((size_t)N * 64); // agg1 / h1 / agg2
    float* bufB = alloc((size_t)N * 64); // hw1 / hw2
    float* pooled = alloc(NG * HID);
    float* counts = alloc(NG);

    float* out = (float*)d_out;

    // 1) degrees & dinv
    k_init_deg<<<(N + 255) / 256, 256, 0, stream>>>(dinv, N);
    k_edge_deg<<<(E + 255) / 256, 256, 0, stream>>>(dst, dinv, E);
    k_dinv<<<(N + 255) / 256, 256, 0, stream>>>(dinv, N);

    // zero pooled + counts
    k_zero<<<(NG * HID + NG + 255) / 256, 256, 0, stream>>>(pooled, NG * HID + NG);
    // note pooled and counts are adjacent-ish but alloc aligned; zero separately
    k_zero<<<1, 64, 0, stream>>>(counts, NG);

    // 2) layer 1: hw1 = x@W1 ; agg1 = hw1*snorm + b1
    k_gemm<FEAT><<<2048, 256, 0, stream>>>(x, W1, b1, dinv, bufB, bufA, N);
    k_scatter<<<8192, 256, 0, stream>>>(src, dst, dinv, bufB, bufA, E);
    k_relu<<<4096, 256, 0, stream>>>(bufA, (long)N * 64);

    // 3) layer 2: hw2 = h1@W2 ; agg2 = hw2*snorm + b2 (agg2 overwrites h1 rows)
    k_gemm<HID><<<2048, 256, 0, stream>>>(bufA, W2, b2, dinv, bufB, bufA, N);
    k_scatter<<<8192, 256, 0, stream>>>(src, dst, dinv, bufB, bufA, E);

    // 4) relu + mean-pool
    k_relu_pool<<<8192, 256, 0, stream>>>(bufA, batch, pooled, counts, N);
    k_pool_div<<<(NG * HID + 255) / 256, 256, 0, stream>>>(pooled, counts);

    // 5) mu / logvar -> out[900:]
    k_heads<<<(2 * NG * LAT + 255) / 256, 256, 0, stream>>>(pooled, Wmu, bmu, Wlv, blv, out);

    // 6) decoder -> out[0:900]
    k_decoder<<<1, 256, 0, stream>>>(Wl1, bl1, Wl2, bl2, We1, be1, We2, be2, out);
}

// Round 2
// 529.448 us; speedup vs baseline: 1.6619x; 1.6619x over previous
//
#include <hip/hip_runtime.h>
#include <hip/hip_bf16.h>
#include <math.h>

// Problem constants (from reference)
#define FEAT 128
#define HID 64
#define LAT 32
#define NG 64
#define MAXN 30
// out layout: adj (30*30=900) | mu (64*32=2048) | logvar (2048)

__global__ void k_init_deg(float* deg, int N) {
    int i = blockIdx.x * blockDim.x + threadIdx.x;
    if (i < N) deg[i] = 1.0f;
}

__global__ void k_edge_deg(const int* dst, float* deg, int E) {
    int i = blockIdx.x * blockDim.x + threadIdx.x;
    if (i < E) atomicAdd(&deg[dst[i]], 1.0f);
}

__global__ void k_dinv(float* deg, int N) {
    int i = blockIdx.x * blockDim.x + threadIdx.x;
    if (i < N) deg[i] = rsqrtf(deg[i]);  // in-place: deg -> dinv
}

__global__ void k_zero(float* p, int n) {
    int i = blockIdx.x * blockDim.x + threadIdx.x;
    if (i < n) p[i] = 0.0f;
}

// Fused GEMM: hw = in @ W  (N x K @ K x 64), and agg-init = hw*snorm + b.
// One wave per row; W staged in LDS.
template <int K>
__global__ __launch_bounds__(256) void k_gemm(const float* __restrict__ in,
                                              const float* __restrict__ W,
                                              const float* __restrict__ b,
                                              const float* __restrict__ dinv,
                                              float* __restrict__ hw,
                                              float* __restrict__ agg,
                                              int N) {
    __shared__ float Wl[K * 64];
    __shared__ float xr[4][K];
    int tid = threadIdx.x;
    for (int i = tid; i < K * 64; i += 256) Wl[i] = W[i];
    __syncthreads();
    int lane = tid & 63;
    int wv = tid >> 6;
    float bias = b[lane];
    int stride = gridDim.x * 4;
    for (int row = blockIdx.x * 4 + wv; row < N; row += stride) {
        for (int k = lane; k < K; k += 64) xr[wv][k] = in[(long)row * K + k];
        float acc = 0.0f;
#pragma unroll
        for (int k = 0; k < K; ++k) acc += xr[wv][k] * Wl[k * 64 + lane];
        float di = dinv[row];
        hw[(long)row * 64 + lane] = acc;
        agg[(long)row * 64 + lane] = acc * (di * di) + bias;
    }
}

// One wave per edge: agg[dst] += hw[src] * dinv[src]*dinv[dst]
__global__ __launch_bounds__(256) void k_scatter(const int* __restrict__ src,
                                                 const int* __restrict__ dst,
                                                 const float* __restrict__ dinv,
                                                 const float* __restrict__ hw,
                                                 float* __restrict__ agg,
                                                 int E) {
    int wid = (blockIdx.x * blockDim.x + threadIdx.x) >> 6;
    int lane = threadIdx.x & 63;
    int nw = (gridDim.x * blockDim.x) >> 6;
    for (int e = wid; e < E; e += nw) {
        int s = src[e], d = dst[e];
        float en = dinv[s] * dinv[d];
        float v = hw[(long)s * 64 + lane] * en;
        atomicAdd(&agg[(long)d * 64 + lane], v);
    }
}

__global__ void k_relu(float* p, long n) {
    long i = (long)blockIdx.x * blockDim.x + threadIdx.x;
    long stride = (long)gridDim.x * blockDim.x;
    for (; i < n; i += stride) p[i] = fmaxf(p[i], 0.0f);
}

// relu + mean-pool: batch is SORTED, so each wave takes a CONTIGUOUS node
// range, register-accumulates per (lane=feature, current graph), and flushes
// one atomicAdd per graph transition. ~4K atomic wave-instrs vs 50K before.
__global__ __launch_bounds__(256) void k_relu_pool(const float* __restrict__ agg,
                                                   const int* __restrict__ batch,
                                                   float* __restrict__ pooled,
                                                   float* __restrict__ counts,
                                                   int N, int rows_per_wave) {
    int wid = blockIdx.x * (blockDim.x >> 6) + (threadIdx.x >> 6);
    int lane = threadIdx.x & 63;
    int i0 = wid * rows_per_wave;
    if (i0 >= N) return;
    int i1 = min(i0 + rows_per_wave, N);
    int cur = batch[i0];
    float acc = 0.0f, cnt = 0.0f;
    for (int i = i0; i < i1; ++i) {
        int g = batch[i];
        if (g != cur) {
            atomicAdd(&pooled[cur * 64 + lane], acc);
            if (lane == 0) atomicAdd(&counts[cur], cnt);
            acc = 0.0f; cnt = 0.0f; cur = g;
        }
        acc += fmaxf(agg[(long)i * 64 + lane], 0.0f);
        cnt += 1.0f;
    }
    atomicAdd(&pooled[cur * 64 + lane], acc);
    if (lane == 0) atomicAdd(&counts[cur], cnt);
}

__global__ void k_pool_div(float* pooled, const float* counts) {
    int i = blockIdx.x * blockDim.x + threadIdx.x;
    if (i < NG * HID) {
        float c = fmaxf(counts[i >> 6], 1.0f);
        pooled[i] /= c;
    }
}

// mu / logvar heads -> out[900 + idx]
__global__ void k_heads(const float* __restrict__ pooled,
                        const float* __restrict__ Wmu, const float* __restrict__ bmu,
                        const float* __restrict__ Wlv, const float* __restrict__ blv,
                        float* __restrict__ out) {
    int idx = blockIdx.x * blockDim.x + threadIdx.x;
    if (idx >= 2 * NG * LAT) return;
    int which = idx >> 11;          // 0: mu, 1: logvar
    int r = idx & (NG * LAT - 1);
    int g = r >> 5, l = r & 31;
    const float* W = which ? Wlv : Wmu;
    const float* b = which ? blv : bmu;
    float s = b[l];
#pragma unroll 8
    for (int h = 0; h < HID; ++h) s += pooled[g * 64 + h] * W[h * 32 + l];
    out[900 + idx] = s;
}

// Single-block decoder: z0 -> hrow -> emb(30x64) -> hi/hj -> adj
__global__ __launch_bounds__(256) void k_decoder(const float* __restrict__ Wl1,
                                                 const float* __restrict__ bl1,
                                                 const float* __restrict__ Wl2,
                                                 const float* __restrict__ bl2,
                                                 const float* __restrict__ We1,
                                                 const float* __restrict__ be1,
                                                 const float* __restrict__ We2,
                                                 const float* __restrict__ be2,
                                                 float* __restrict__ out) {
    __shared__ float z0[LAT];
    __shared__ float hr[HID];
    __shared__ float emb[MAXN * HID];
    __shared__ float hi[MAXN * HID];
    __shared__ float hj[MAXN * HID];
    __shared__ float sbe1[HID];
    __shared__ float sWe2[HID];
    int tid = threadIdx.x;
    if (tid < LAT) z0[tid] = out[900 + tid];  // mu row of graph 0
    if (tid < HID) { sbe1[tid] = be1[tid]; sWe2[tid] = We2[tid]; }
    __syncthreads();
    if (tid < HID) {
        float s = bl1[tid];
#pragma unroll
        for (int l = 0; l < LAT; ++l) s += z0[l] * Wl1[l * HID + tid];
        hr[tid] = fmaxf(s, 0.0f);
    }
    __syncthreads();
    for (int i = tid; i < MAXN * HID; i += 256) {
        float s = bl2[i];
#pragma unroll 8
        for (int h = 0; h < HID; ++h) s += hr[h] * Wl2[h * (HID * MAXN) + i];
        emb[i] = s;
    }
    __syncthreads();
    for (int i = tid; i < MAXN * HID; i += 256) {
        int n = i >> 6, k = i & 63;
        float a = 0.0f, bb = 0.0f;
#pragma unroll 8
        for (int f = 0; f < HID; ++f) {
            float e = emb[n * 64 + f];
            a += e * We1[f * 64 + k];
            bb += e * We1[(64 + f) * 64 + k];
        }
        hi[i] = a;
        hj[i] = bb;
    }
    __syncthreads();
    float bias2 = be2[0];
    for (int idx = tid; idx < MAXN * MAXN; idx += 256) {
        int i = idx / MAXN, j = idx % MAXN;
        if (i == j) { out[idx] = 0.0f; continue; }
        int a = i < j ? i : j;
        int b = i < j ? j : i;
        float s = bias2;
#pragma unroll 8
        for (int k = 0; k < HID; ++k)
            s += fmaxf(hi[a * 64 + k] + hj[b * 64 + k] + sbe1[k], 0.0f) * sWe2[k];
        out[idx] = 1.0f / (1.0f + expf(-s));
    }
}

extern "C" void kernel_launch(void* const* d_in, const int* in_sizes, int n_in,
                              void* d_out, int out_size, void* d_ws, size_t ws_size,
                              hipStream_t stream) {
    const float* x = (const float*)d_in[0];
    const int* ei = (const int*)d_in[1];
    const int* batch = (const int*)d_in[2];
    const float* W1 = (const float*)d_in[4];
    const float* b1 = (const float*)d_in[5];
    const float* W2 = (const float*)d_in[6];
    const float* b2 = (const float*)d_in[7];
    const float* Wmu = (const float*)d_in[8];
    const float* bmu = (const float*)d_in[9];
    const float* Wlv = (const float*)d_in[10];
    const float* blv = (const float*)d_in[11];
    const float* Wl1 = (const float*)d_in[12];
    const float* bl1 = (const float*)d_in[13];
    const float* Wl2 = (const float*)d_in[14];
    const float* bl2 = (const float*)d_in[15];
    const float* We1 = (const float*)d_in[16];
    const float* be1 = (const float*)d_in[17];
    const float* We2 = (const float*)d_in[18];
    const float* be2 = (const float*)d_in[19];

    const int N = in_sizes[2];            // 50000
    const int E = in_sizes[1] / 2;        // 800000
    const int* src = ei;
    const int* dst = ei + E;

    // workspace carve-up (all f32), 256B aligned
    char* ws = (char*)d_ws;
    size_t off = 0;
    auto alloc = [&](size_t nfloats) {
        float* p = (float*)(ws + off);
        off = (off + nfloats * 4 + 255) & ~(size_t)255;
        return p;
    };
    float* dinv = alloc(N);              // deg -> dinv in place
    float* bufA = alloc((size_t)N * 64); // agg1 / h1 / agg2
    float* bufB = alloc((size_t)N * 64); // hw1 / hw2
    float* pooled = alloc(NG * HID);
    float* counts = alloc(NG);

    float* out = (float*)d_out;

    // 1) degrees & dinv
    k_init_deg<<<(N + 255) / 256, 256, 0, stream>>>(dinv, N);
    k_edge_deg<<<(E + 255) / 256, 256, 0, stream>>>(dst, dinv, E);
    k_dinv<<<(N + 255) / 256, 256, 0, stream>>>(dinv, N);

    // zero pooled + counts
    k_zero<<<(NG * HID + NG + 255) / 256, 256, 0, stream>>>(pooled, NG * HID + NG);
    k_zero<<<1, 64, 0, stream>>>(counts, NG);

    // 2) layer 1: hw1 = x@W1 ; agg1 = hw1*snorm + b1
    k_gemm<FEAT><<<2048, 256, 0, stream>>>(x, W1, b1, dinv, bufB, bufA, N);
    k_scatter<<<8192, 256, 0, stream>>>(src, dst, dinv, bufB, bufA, E);
    k_relu<<<4096, 256, 0, stream>>>(bufA, (long)N * 64);

    // 3) layer 2: hw2 = h1@W2 ; agg2 = hw2*snorm + b2
    k_gemm<HID><<<2048, 256, 0, stream>>>(bufA, W2, b2, dinv, bufB, bufA, N);
    k_scatter<<<8192, 256, 0, stream>>>(src, dst, dinv, bufB, bufA, E);

    // 4) relu + mean-pool (contiguous ranges, register accumulation)
    {
        const int waves = 2048;              // 512 blocks x 4 waves
        int rpw = (N + waves - 1) / waves;   // ~25 rows/wave
        k_relu_pool<<<512, 256, 0, stream>>>(bufA, batch, pooled, counts, N, rpw);
    }
    k_pool_div<<<(NG * HID + 255) / 256, 256, 0, stream>>>(pooled, counts);

    // 5) mu / logvar -> out[900:]
    k_heads<<<(2 * NG * LAT + 255) / 256, 256, 0, stream>>>(pooled, Wmu, bmu, Wlv, blv, out);

    // 6) decoder -> out[0:900]
    k_decoder<<<1, 256, 0, stream>>>(Wl1, bl1, Wl2, bl2, We1, be1, We2, be2, out);
}

// Round 3
// 296.245 us; speedup vs baseline: 2.9701x; 1.7872x over previous
//
#include <hip/hip_runtime.h>
#include <hip/hip_bf16.h>
#include <math.h>

// Problem constants (from reference)
#define FEAT 128
#define HID 64
#define LAT 32
#define NG 64
#define MAXN 30
#define SCAN_CHUNK 512
// out layout: adj (30*30=900) | mu (64*32=2048) | logvar (2048)

__global__ void k_zero_i(int* p, int n) {
    int i = blockIdx.x * blockDim.x + threadIdx.x;
    if (i < n) p[i] = 0;
}

__global__ void k_zero_f(float* p, int n) {
    int i = blockIdx.x * blockDim.x + threadIdx.x;
    if (i < n) p[i] = 0.0f;
}

// in-degree histogram
__global__ void k_hist(const int* __restrict__ dst, int* __restrict__ hist, int E) {
    int i = blockIdx.x * blockDim.x + threadIdx.x;
    if (i < E) atomicAdd(&hist[dst[i]], 1);
}

// block-level inclusive scan (Hillis-Steele), chunk = 512
__global__ __launch_bounds__(SCAN_CHUNK) void k_scan1(const int* __restrict__ hist,
                                                      int* __restrict__ incl,
                                                      int* __restrict__ bsum, int N) {
    __shared__ int buf[SCAN_CHUNK];
    int i = blockIdx.x * SCAN_CHUNK + threadIdx.x;
    int v = (i < N) ? hist[i] : 0;
    buf[threadIdx.x] = v;
    __syncthreads();
    for (int d = 1; d < SCAN_CHUNK; d <<= 1) {
        int t = (threadIdx.x >= d) ? buf[threadIdx.x - d] : 0;
        __syncthreads();
        buf[threadIdx.x] += t;
        __syncthreads();
    }
    if (i < N) incl[i] = buf[threadIdx.x];
    if (threadIdx.x == SCAN_CHUNK - 1) bsum[blockIdx.x] = buf[threadIdx.x];
}

// scan of block sums (single block, up to 128 blocks) -> exclusive
__global__ __launch_bounds__(128) void k_scan_top(int* bsum, int nb) {
    __shared__ int buf[128];
    int v = (threadIdx.x < nb) ? bsum[threadIdx.x] : 0;
    buf[threadIdx.x] = v;
    __syncthreads();
    for (int d = 1; d < 128; d <<= 1) {
        int t = (threadIdx.x >= d) ? buf[threadIdx.x - d] : 0;
        __syncthreads();
        buf[threadIdx.x] += t;
        __syncthreads();
    }
    if (threadIdx.x < nb) bsum[threadIdx.x] = buf[threadIdx.x] - v;  // exclusive
}

// finalize: exclusive offsets, cursor copy, dinv = rsqrt(1 + indeg)
__global__ void k_scan_add(const int* __restrict__ hist, const int* __restrict__ incl,
                           const int* __restrict__ bsum, int* __restrict__ off,
                           int* __restrict__ cursor, float* __restrict__ dinv,
                           int N, int E) {
    int i = blockIdx.x * blockDim.x + threadIdx.x;
    if (i < N) {
        int h = hist[i];
        int o = incl[i] - h + bsum[i / SCAN_CHUNK];
        off[i] = o;
        cursor[i] = o;
        dinv[i] = rsqrtf(1.0f + (float)h);
    }
    if (i == 0) off[N] = E;
}

// bucket-fill: dst-sorted src ids + per-edge enorm
__global__ void k_sortedges(const int* __restrict__ src, const int* __restrict__ dst,
                            const float* __restrict__ dinv, int* __restrict__ cursor,
                            int* __restrict__ ssrc, float* __restrict__ sen, int E) {
    int e = blockIdx.x * blockDim.x + threadIdx.x;
    if (e < E) {
        int s = src[e], d = dst[e];
        int pos = atomicAdd(&cursor[d], 1);
        ssrc[pos] = s;
        sen[pos] = dinv[s] * dinv[d];
    }
}

// GEMM: hw = in @ W  (N x K @ K x 64). One wave per row; W staged in LDS.
template <int K>
__global__ __launch_bounds__(256) void k_gemm(const float* __restrict__ in,
                                              const float* __restrict__ W,
                                              float* __restrict__ hw, int N) {
    __shared__ float Wl[K * 64];
    __shared__ float xr[4][K];
    int tid = threadIdx.x;
    for (int i = tid; i < K * 64; i += 256) Wl[i] = W[i];
    __syncthreads();
    int lane = tid & 63;
    int wv = tid >> 6;
    int stride = gridDim.x * 4;
    for (int row = blockIdx.x * 4 + wv; row < N; row += stride) {
        for (int k = lane; k < K; k += 64) xr[wv][k] = in[(long)row * K + k];
        float acc = 0.0f;
#pragma unroll
        for (int k = 0; k < K; ++k) acc += xr[wv][k] * Wl[k * 64 + lane];
        hw[(long)row * 64 + lane] = acc;
    }
}

// CSR gather: out[d] = sum_in-edges hw[s]*en + hw[d]*snorm + b  (+optional relu)
// One wave per dst node; lane = feature. Read-only gathers -> no L2 ping-pong.
__global__ __launch_bounds__(256) void k_gather(const float* __restrict__ hw,
                                                const int* __restrict__ ssrc,
                                                const float* __restrict__ sen,
                                                const int* __restrict__ off,
                                                const float* __restrict__ dinv,
                                                const float* __restrict__ b,
                                                float* __restrict__ outb,
                                                int N, int do_relu) {
    int wid = blockIdx.x * 4 + (threadIdx.x >> 6);
    int lane = threadIdx.x & 63;
    if (wid >= N) return;
    int j0 = off[wid], j1 = off[wid + 1];
    float di = dinv[wid];
    float acc0 = hw[(long)wid * 64 + lane] * (di * di) + b[lane];
    float acc1 = 0.0f;
    int j = j0;
    for (; j + 3 < j1; j += 4) {
        int s0 = ssrc[j], s1 = ssrc[j + 1], s2 = ssrc[j + 2], s3 = ssrc[j + 3];
        float e0 = sen[j], e1 = sen[j + 1], e2 = sen[j + 2], e3 = sen[j + 3];
        float v0 = hw[(long)s0 * 64 + lane];
        float v1 = hw[(long)s1 * 64 + lane];
        float v2 = hw[(long)s2 * 64 + lane];
        float v3 = hw[(long)s3 * 64 + lane];
        acc0 += v0 * e0;
        acc1 += v1 * e1;
        acc0 += v2 * e2;
        acc1 += v3 * e3;
    }
    for (; j < j1; ++j) {
        int s = ssrc[j];
        acc0 += hw[(long)s * 64 + lane] * sen[j];
    }
    float acc = acc0 + acc1;
    if (do_relu) acc = fmaxf(acc, 0.0f);
    outb[(long)wid * 64 + lane] = acc;
}

// relu + mean-pool: batch is SORTED; each wave owns a contiguous node range,
// register-accumulates, flushes one atomicAdd per graph transition.
__global__ __launch_bounds__(256) void k_relu_pool(const float* __restrict__ agg,
                                                   const int* __restrict__ batch,
                                                   float* __restrict__ pooled,
                                                   float* __restrict__ counts,
                                                   int N, int rows_per_wave) {
    int wid = blockIdx.x * (blockDim.x >> 6) + (threadIdx.x >> 6);
    int lane = threadIdx.x & 63;
    int i0 = wid * rows_per_wave;
    if (i0 >= N) return;
    int i1 = min(i0 + rows_per_wave, N);
    int cur = batch[i0];
    float acc = 0.0f, cnt = 0.0f;
    for (int i = i0; i < i1; ++i) {
        int g = batch[i];
        if (g != cur) {
            atomicAdd(&pooled[cur * 64 + lane], acc);
            if (lane == 0) atomicAdd(&counts[cur], cnt);
            acc = 0.0f; cnt = 0.0f; cur = g;
        }
        acc += fmaxf(agg[(long)i * 64 + lane], 0.0f);
        cnt += 1.0f;
    }
    atomicAdd(&pooled[cur * 64 + lane], acc);
    if (lane == 0) atomicAdd(&counts[cur], cnt);
}

__global__ void k_pool_div(float* pooled, const float* counts) {
    int i = blockIdx.x * blockDim.x + threadIdx.x;
    if (i < NG * HID) {
        float c = fmaxf(counts[i >> 6], 1.0f);
        pooled[i] /= c;
    }
}

// mu / logvar heads -> out[900 + idx]
__global__ void k_heads(const float* __restrict__ pooled,
                        const float* __restrict__ Wmu, const float* __restrict__ bmu,
                        const float* __restrict__ Wlv, const float* __restrict__ blv,
                        float* __restrict__ out) {
    int idx = blockIdx.x * blockDim.x + threadIdx.x;
    if (idx >= 2 * NG * LAT) return;
    int which = idx >> 11;          // 0: mu, 1: logvar
    int r = idx & (NG * LAT - 1);
    int g = r >> 5, l = r & 31;
    const float* W = which ? Wlv : Wmu;
    const float* b = which ? blv : bmu;
    float s = b[l];
#pragma unroll 8
    for (int h = 0; h < HID; ++h) s += pooled[g * 64 + h] * W[h * 32 + l];
    out[900 + idx] = s;
}

// Single-block decoder: z0 -> hrow -> emb(30x64) -> hi/hj -> adj
__global__ __launch_bounds__(256) void k_decoder(const float* __restrict__ Wl1,
                                                 const float* __restrict__ bl1,
                                                 const float* __restrict__ Wl2,
                                                 const float* __restrict__ bl2,
                                                 const float* __restrict__ We1,
                                                 const float* __restrict__ be1,
                                                 const float* __restrict__ We2,
                                                 const float* __restrict__ be2,
                                                 float* __restrict__ out) {
    __shared__ float z0[LAT];
    __shared__ float hr[HID];
    __shared__ float emb[MAXN * HID];
    __shared__ float hi[MAXN * HID];
    __shared__ float hj[MAXN * HID];
    __shared__ float sbe1[HID];
    __shared__ float sWe2[HID];
    int tid = threadIdx.x;
    if (tid < LAT) z0[tid] = out[900 + tid];  // mu row of graph 0
    if (tid < HID) { sbe1[tid] = be1[tid]; sWe2[tid] = We2[tid]; }
    __syncthreads();
    if (tid < HID) {
        float s = bl1[tid];
#pragma unroll
        for (int l = 0; l < LAT; ++l) s += z0[l] * Wl1[l * HID + tid];
        hr[tid] = fmaxf(s, 0.0f);
    }
    __syncthreads();
    for (int i = tid; i < MAXN * HID; i += 256) {
        float s = bl2[i];
#pragma unroll 8
        for (int h = 0; h < HID; ++h) s += hr[h] * Wl2[h * (HID * MAXN) + i];
        emb[i] = s;
    }
    __syncthreads();
    for (int i = tid; i < MAXN * HID; i += 256) {
        int n = i >> 6, k = i & 63;
        float a = 0.0f, bb = 0.0f;
#pragma unroll 8
        for (int f = 0; f < HID; ++f) {
            float e = emb[n * 64 + f];
            a += e * We1[f * 64 + k];
            bb += e * We1[(64 + f) * 64 + k];
        }
        hi[i] = a;
        hj[i] = bb;
    }
    __syncthreads();
    float bias2 = be2[0];
    for (int idx = tid; idx < MAXN * MAXN; idx += 256) {
        int i = idx / MAXN, j = idx % MAXN;
        if (i == j) { out[idx] = 0.0f; continue; }
        int a = i < j ? i : j;
        int b = i < j ? j : i;
        float s = bias2;
#pragma unroll 8
        for (int k = 0; k < HID; ++k)
            s += fmaxf(hi[a * 64 + k] + hj[b * 64 + k] + sbe1[k], 0.0f) * sWe2[k];
        out[idx] = 1.0f / (1.0f + expf(-s));
    }
}

extern "C" void kernel_launch(void* const* d_in, const int* in_sizes, int n_in,
                              void* d_out, int out_size, void* d_ws, size_t ws_size,
                              hipStream_t stream) {
    const float* x = (const float*)d_in[0];
    const int* ei = (const int*)d_in[1];
    const int* batch = (const int*)d_in[2];
    const float* W1 = (const float*)d_in[4];
    const float* b1 = (const float*)d_in[5];
    const float* W2 = (const float*)d_in[6];
    const float* b2 = (const float*)d_in[7];
    const float* Wmu = (const float*)d_in[8];
    const float* bmu = (const float*)d_in[9];
    const float* Wlv = (const float*)d_in[10];
    const float* blv = (const float*)d_in[11];
    const float* Wl1 = (const float*)d_in[12];
    const float* bl1 = (const float*)d_in[13];
    const float* Wl2 = (const float*)d_in[14];
    const float* bl2 = (const float*)d_in[15];
    const float* We1 = (const float*)d_in[16];
    const float* be1 = (const float*)d_in[17];
    const float* We2 = (const float*)d_in[18];
    const float* be2 = (const float*)d_in[19];

    const int N = in_sizes[2];            // 50000
    const int E = in_sizes[1] / 2;        // 800000
    const int* src = ei;
    const int* dst = ei + E;

    // workspace carve-up, 256B aligned
    char* ws = (char*)d_ws;
    size_t off_b = 0;
    auto alloc = [&](size_t nbytes) {
        void* p = (void*)(ws + off_b);
        off_b = (off_b + nbytes + 255) & ~(size_t)255;
        return p;
    };
    float* dinv   = (float*)alloc((size_t)N * 4);
    float* bufA   = (float*)alloc((size_t)N * 64 * 4);  // h1 / agg2
    float* bufB   = (float*)alloc((size_t)N * 64 * 4);  // hw1 / hw2
    float* pooled = (float*)alloc(NG * HID * 4);
    float* counts = (float*)alloc(NG * 4);
    int*   hist   = (int*)alloc((size_t)N * 4);
    int*   incl   = (int*)alloc((size_t)N * 4);
    int*   bsum   = (int*)alloc(128 * 4);
    int*   offs   = (int*)alloc(((size_t)N + 1) * 4);
    int*   cursor = (int*)alloc((size_t)N * 4);
    int*   ssrc   = (int*)alloc((size_t)E * 4);
    float* sen    = (float*)alloc((size_t)E * 4);

    float* out = (float*)d_out;
    const int nb_scan = (N + SCAN_CHUNK - 1) / SCAN_CHUNK;  // 98

    // 1) CSR build: hist -> scan -> offsets/dinv -> bucket fill
    k_zero_i<<<(N + 255) / 256, 256, 0, stream>>>(hist, N);
    k_hist<<<(E + 255) / 256, 256, 0, stream>>>(dst, hist, E);
    k_scan1<<<nb_scan, SCAN_CHUNK, 0, stream>>>(hist, incl, bsum, N);
    k_scan_top<<<1, 128, 0, stream>>>(bsum, nb_scan);
    k_scan_add<<<(N + 255) / 256, 256, 0, stream>>>(hist, incl, bsum, offs, cursor, dinv, N, E);
    k_sortedges<<<(E + 255) / 256, 256, 0, stream>>>(src, dst, dinv, cursor, ssrc, sen, E);

    // zero pooled + counts
    k_zero_f<<<(NG * HID + 255) / 256, 256, 0, stream>>>(pooled, NG * HID);
    k_zero_f<<<1, 64, 0, stream>>>(counts, NG);

    // 2) layer 1: hw1 = x@W1 ; h1 = relu(gather)
    k_gemm<FEAT><<<2048, 256, 0, stream>>>(x, W1, bufB, N);
    k_gather<<<(N + 3) / 4, 256, 0, stream>>>(bufB, ssrc, sen, offs, dinv, b1, bufA, N, 1);

    // 3) layer 2: hw2 = h1@W2 ; agg2 = gather (relu deferred to pool)
    k_gemm<HID><<<2048, 256, 0, stream>>>(bufA, W2, bufB, N);
    k_gather<<<(N + 3) / 4, 256, 0, stream>>>(bufB, ssrc, sen, offs, dinv, b2, bufA, N, 0);

    // 4) relu + mean-pool (contiguous ranges, register accumulation)
    {
        const int waves = 2048;
        int rpw = (N + waves - 1) / waves;
        k_relu_pool<<<512, 256, 0, stream>>>(bufA, batch, pooled, counts, N, rpw);
    }
    k_pool_div<<<(NG * HID + 255) / 256, 256, 0, stream>>>(pooled, counts);

    // 5) mu / logvar -> out[900:]
    k_heads<<<(2 * NG * LAT + 255) / 256, 256, 0, stream>>>(pooled, Wmu, bmu, Wlv, blv, out);

    // 6) decoder -> out[0:900]
    k_decoder<<<1, 256, 0, stream>>>(Wl1, bl1, Wl2, bl2, We1, be1, We2, be2, out);
}

// Round 4
// 261.871 us; speedup vs baseline: 3.3600x; 1.1313x over previous
//
#include <hip/hip_runtime.h>
#include <hip/hip_bf16.h>
#include <math.h>

// Problem constants (from reference)
#define FEAT 128
#define HID 64
#define LAT 32
#define NG 64
#define MAXN 30
#define SCAN_CHUNK 512
// out layout: adj (30*30=900) | mu (64*32=2048) | logvar (2048)

__global__ void k_zero_i(int* p, int n) {
    int i = blockIdx.x * blockDim.x + threadIdx.x;
    if (i < n) p[i] = 0;
}

__global__ void k_zero_f(float* p, int n) {
    int i = blockIdx.x * blockDim.x + threadIdx.x;
    if (i < n) p[i] = 0.0f;
}

// in-degree histogram
__global__ void k_hist(const int* __restrict__ dst, int* __restrict__ hist, int E) {
    int i = blockIdx.x * blockDim.x + threadIdx.x;
    if (i < E) atomicAdd(&hist[dst[i]], 1);
}

// block-level inclusive scan (Hillis-Steele), chunk = 512
__global__ __launch_bounds__(SCAN_CHUNK) void k_scan1(const int* __restrict__ hist,
                                                      int* __restrict__ incl,
                                                      int* __restrict__ bsum, int N) {
    __shared__ int buf[SCAN_CHUNK];
    int i = blockIdx.x * SCAN_CHUNK + threadIdx.x;
    int v = (i < N) ? hist[i] : 0;
    buf[threadIdx.x] = v;
    __syncthreads();
    for (int d = 1; d < SCAN_CHUNK; d <<= 1) {
        int t = (threadIdx.x >= d) ? buf[threadIdx.x - d] : 0;
        __syncthreads();
        buf[threadIdx.x] += t;
        __syncthreads();
    }
    if (i < N) incl[i] = buf[threadIdx.x];
    if (threadIdx.x == SCAN_CHUNK - 1) bsum[blockIdx.x] = buf[threadIdx.x];
}

// scan of block sums (single block, up to 128 blocks) -> exclusive
__global__ __launch_bounds__(128) void k_scan_top(int* bsum, int nb) {
    __shared__ int buf[128];
    int v = (threadIdx.x < nb) ? bsum[threadIdx.x] : 0;
    buf[threadIdx.x] = v;
    __syncthreads();
    for (int d = 1; d < 128; d <<= 1) {
        int t = (threadIdx.x >= d) ? buf[threadIdx.x - d] : 0;
        __syncthreads();
        buf[threadIdx.x] += t;
        __syncthreads();
    }
    if (threadIdx.x < nb) bsum[threadIdx.x] = buf[threadIdx.x] - v;  // exclusive
}

// finalize: exclusive offsets, cursor copy, dinv = rsqrt(1 + indeg)
__global__ void k_scan_add(const int* __restrict__ hist, const int* __restrict__ incl,
                           const int* __restrict__ bsum, int* __restrict__ off,
                           int* __restrict__ cursor, float* __restrict__ dinv,
                           int N, int E) {
    int i = blockIdx.x * blockDim.x + threadIdx.x;
    if (i < N) {
        int h = hist[i];
        int o = incl[i] - h + bsum[i / SCAN_CHUNK];
        off[i] = o;
        cursor[i] = o;
        dinv[i] = rsqrtf(1.0f + (float)h);
    }
    if (i == 0) off[N] = E;
}

// bucket-fill: dst-sorted (src, enorm) interleaved as one int2 store per edge
__global__ void k_sortedges(const int* __restrict__ src, const int* __restrict__ dst,
                            const float* __restrict__ dinv, int* __restrict__ cursor,
                            int2* __restrict__ sedge, int E) {
    int e = blockIdx.x * blockDim.x + threadIdx.x;
    if (e < E) {
        int s = src[e], d = dst[e];
        int pos = atomicAdd(&cursor[d], 1);
        float en = dinv[s] * dinv[d];
        sedge[pos] = make_int2(s, __float_as_int(en));
    }
}

// GEMM: hw = in @ W  (N x K @ K x 64). One wave per row; W staged in LDS.
template <int K>
__global__ __launch_bounds__(256) void k_gemm(const float* __restrict__ in,
                                              const float* __restrict__ W,
                                              float* __restrict__ hw, int N) {
    __shared__ float Wl[K * 64];
    __shared__ float xr[4][K];
    int tid = threadIdx.x;
    for (int i = tid; i < K * 64; i += 256) Wl[i] = W[i];
    __syncthreads();
    int lane = tid & 63;
    int wv = tid >> 6;
    int stride = gridDim.x * 4;
    for (int row = blockIdx.x * 4 + wv; row < N; row += stride) {
        for (int k = lane; k < K; k += 64) xr[wv][k] = in[(long)row * K + k];
        float acc = 0.0f;
#pragma unroll
        for (int k = 0; k < K; ++k) acc += xr[wv][k] * Wl[k * 64 + lane];
        hw[(long)row * 64 + lane] = acc;
    }
}

// CSR gather: out[d] = sum_in-edges hw[s]*en + hw[d]*snorm + b  (+optional relu)
// One wave per dst node; lane = feature. Read-only gathers -> no L2 ping-pong.
__global__ __launch_bounds__(256) void k_gather(const float* __restrict__ hw,
                                                const int2* __restrict__ sedge,
                                                const int* __restrict__ off,
                                                const float* __restrict__ dinv,
                                                const float* __restrict__ b,
                                                float* __restrict__ outb,
                                                int N, int do_relu) {
    int wid = blockIdx.x * 4 + (threadIdx.x >> 6);
    int lane = threadIdx.x & 63;
    if (wid >= N) return;
    int j0 = off[wid], j1 = off[wid + 1];
    float di = dinv[wid];
    float acc0 = hw[(long)wid * 64 + lane] * (di * di) + b[lane];
    float acc1 = 0.0f;
    int j = j0;
    for (; j + 3 < j1; j += 4) {
        int2 e0 = sedge[j], e1 = sedge[j + 1], e2 = sedge[j + 2], e3 = sedge[j + 3];
        float v0 = hw[(long)e0.x * 64 + lane];
        float v1 = hw[(long)e1.x * 64 + lane];
        float v2 = hw[(long)e2.x * 64 + lane];
        float v3 = hw[(long)e3.x * 64 + lane];
        acc0 += v0 * __int_as_float(e0.y);
        acc1 += v1 * __int_as_float(e1.y);
        acc0 += v2 * __int_as_float(e2.y);
        acc1 += v3 * __int_as_float(e3.y);
    }
    for (; j < j1; ++j) {
        int2 e = sedge[j];
        acc0 += hw[(long)e.x * 64 + lane] * __int_as_float(e.y);
    }
    float acc = acc0 + acc1;
    if (do_relu) acc = fmaxf(acc, 0.0f);
    outb[(long)wid * 64 + lane] = acc;
}

// relu + mean-pool: batch is SORTED; each wave owns a contiguous node range,
// register-accumulates, flushes one atomicAdd per graph transition.
__global__ __launch_bounds__(256) void k_relu_pool(const float* __restrict__ agg,
                                                   const int* __restrict__ batch,
                                                   float* __restrict__ pooled,
                                                   float* __restrict__ counts,
                                                   int N, int rows_per_wave) {
    int wid = blockIdx.x * (blockDim.x >> 6) + (threadIdx.x >> 6);
    int lane = threadIdx.x & 63;
    int i0 = wid * rows_per_wave;
    if (i0 >= N) return;
    int i1 = min(i0 + rows_per_wave, N);
    int cur = batch[i0];
    float acc = 0.0f, cnt = 0.0f;
    for (int i = i0; i < i1; ++i) {
        int g = batch[i];
        if (g != cur) {
            atomicAdd(&pooled[cur * 64 + lane], acc);
            if (lane == 0) atomicAdd(&counts[cur], cnt);
            acc = 0.0f; cnt = 0.0f; cur = g;
        }
        acc += fmaxf(agg[(long)i * 64 + lane], 0.0f);
        cnt += 1.0f;
    }
    atomicAdd(&pooled[cur * 64 + lane], acc);
    if (lane == 0) atomicAdd(&counts[cur], cnt);
}

__global__ void k_pool_div(float* pooled, const float* counts) {
    int i = blockIdx.x * blockDim.x + threadIdx.x;
    if (i < NG * HID) {
        float c = fmaxf(counts[i >> 6], 1.0f);
        pooled[i] /= c;
    }
}

// mu / logvar heads -> out[900 + idx]
__global__ void k_heads(const float* __restrict__ pooled,
                        const float* __restrict__ Wmu, const float* __restrict__ bmu,
                        const float* __restrict__ Wlv, const float* __restrict__ blv,
                        float* __restrict__ out) {
    int idx = blockIdx.x * blockDim.x + threadIdx.x;
    if (idx >= 2 * NG * LAT) return;
    int which = idx >> 11;          // 0: mu, 1: logvar
    int r = idx & (NG * LAT - 1);
    int g = r >> 5, l = r & 31;
    const float* W = which ? Wlv : Wmu;
    const float* b = which ? blv : bmu;
    float s = b[l];
#pragma unroll 8
    for (int h = 0; h < HID; ++h) s += pooled[g * 64 + h] * W[h * 32 + l];
    out[900 + idx] = s;
}

// Decoder stage 1: 30 blocks x 64 threads. Each block redundantly computes
// hr = relu(z0@Wl1+bl1) (cheap), then its node's emb row and hi/hj rows.
// Parallelizes the Wl2 (491KB) / We1 (32KB) reads across 30 CUs.
__global__ __launch_bounds__(64) void k_dec1(const float* __restrict__ Wl1,
                                             const float* __restrict__ bl1,
                                             const float* __restrict__ Wl2,
                                             const float* __restrict__ bl2,
                                             const float* __restrict__ We1,
                                             const float* __restrict__ out,
                                             float* __restrict__ hi,
                                             float* __restrict__ hj) {
    __shared__ float z0[LAT];
    __shared__ float hr[HID];
    __shared__ float em[HID];
    int tid = threadIdx.x;
    int n = blockIdx.x;
    if (tid < LAT) z0[tid] = out[900 + tid];  // mu row of graph 0
    __syncthreads();
    float s = bl1[tid];
#pragma unroll
    for (int l = 0; l < LAT; ++l) s += z0[l] * Wl1[l * HID + tid];
    hr[tid] = fmaxf(s, 0.0f);
    __syncthreads();
    float e = bl2[n * HID + tid];
#pragma unroll 8
    for (int h = 0; h < HID; ++h) e += hr[h] * Wl2[h * (HID * MAXN) + n * HID + tid];
    em[tid] = e;
    __syncthreads();
    float a = 0.0f, bb = 0.0f;
#pragma unroll 8
    for (int f = 0; f < HID; ++f) {
        float ev = em[f];
        a += ev * We1[f * HID + tid];
        bb += ev * We1[(HID + f) * HID + tid];
    }
    hi[n * HID + tid] = a;
    hj[n * HID + tid] = bb;
}

// Decoder stage 2: single block, adj from LDS-staged hi/hj (stride-65 pad).
__global__ __launch_bounds__(256) void k_dec2(const float* __restrict__ hi,
                                              const float* __restrict__ hj,
                                              const float* __restrict__ be1,
                                              const float* __restrict__ We2,
                                              const float* __restrict__ be2,
                                              float* __restrict__ out) {
    __shared__ float shi[MAXN * 65];
    __shared__ float shj[MAXN * 65];
    __shared__ float sbe[HID];
    __shared__ float sw[HID];
    int tid = threadIdx.x;
    for (int i = tid; i < MAXN * HID; i += 256) {
        int n = i >> 6, k = i & 63;
        shi[n * 65 + k] = hi[i];
        shj[n * 65 + k] = hj[i];
    }
    if (tid < HID) { sbe[tid] = be1[tid]; sw[tid] = We2[tid]; }
    __syncthreads();
    float bias2 = be2[0];
    for (int idx = tid; idx < MAXN * MAXN; idx += 256) {
        int i = idx / MAXN, j = idx % MAXN;
        if (i == j) { out[idx] = 0.0f; continue; }
        int a = i < j ? i : j;
        int b = i < j ? j : i;
        float s = bias2;
#pragma unroll 8
        for (int k = 0; k < HID; ++k)
            s += fmaxf(shi[a * 65 + k] + shj[b * 65 + k] + sbe[k], 0.0f) * sw[k];
        out[idx] = 1.0f / (1.0f + expf(-s));
    }
}

extern "C" void kernel_launch(void* const* d_in, const int* in_sizes, int n_in,
                              void* d_out, int out_size, void* d_ws, size_t ws_size,
                              hipStream_t stream) {
    const float* x = (const float*)d_in[0];
    const int* ei = (const int*)d_in[1];
    const int* batch = (const int*)d_in[2];
    const float* W1 = (const float*)d_in[4];
    const float* b1 = (const float*)d_in[5];
    const float* W2 = (const float*)d_in[6];
    const float* b2 = (const float*)d_in[7];
    const float* Wmu = (const float*)d_in[8];
    const float* bmu = (const float*)d_in[9];
    const float* Wlv = (const float*)d_in[10];
    const float* blv = (const float*)d_in[11];
    const float* Wl1 = (const float*)d_in[12];
    const float* bl1 = (const float*)d_in[13];
    const float* Wl2 = (const float*)d_in[14];
    const float* bl2 = (const float*)d_in[15];
    const float* We1 = (const float*)d_in[16];
    const float* be1 = (const float*)d_in[17];
    const float* We2 = (const float*)d_in[18];
    const float* be2 = (const float*)d_in[19];

    const int N = in_sizes[2];            // 50000
    const int E = in_sizes[1] / 2;        // 800000
    const int* src = ei;
    const int* dst = ei + E;

    // workspace carve-up, 256B aligned
    char* ws = (char*)d_ws;
    size_t off_b = 0;
    auto alloc = [&](size_t nbytes) {
        void* p = (void*)(ws + off_b);
        off_b = (off_b + nbytes + 255) & ~(size_t)255;
        return p;
    };
    float* dinv   = (float*)alloc((size_t)N * 4);
    float* bufA   = (float*)alloc((size_t)N * 64 * 4);  // h1 / agg2
    float* bufB   = (float*)alloc((size_t)N * 64 * 4);  // hw1 / hw2
    float* pooled = (float*)alloc((NG * HID + NG) * 4); // pooled | counts contiguous
    float* counts = pooled + NG * HID;
    int*   hist   = (int*)alloc((size_t)N * 4);
    int*   incl   = (int*)alloc((size_t)N * 4);
    int*   bsum   = (int*)alloc(128 * 4);
    int*   offs   = (int*)alloc(((size_t)N + 1) * 4);
    int*   cursor = (int*)alloc((size_t)N * 4);
    int2*  sedge  = (int2*)alloc((size_t)E * 8);
    float* dhi    = (float*)alloc(MAXN * HID * 4);
    float* dhj    = (float*)alloc(MAXN * HID * 4);

    float* out = (float*)d_out;
    const int nb_scan = (N + SCAN_CHUNK - 1) / SCAN_CHUNK;  // 98

    // 1) CSR build: hist -> scan -> offsets/dinv -> bucket fill
    k_zero_i<<<(N + 255) / 256, 256, 0, stream>>>(hist, N);
    k_hist<<<(E + 255) / 256, 256, 0, stream>>>(dst, hist, E);
    k_scan1<<<nb_scan, SCAN_CHUNK, 0, stream>>>(hist, incl, bsum, N);
    k_scan_top<<<1, 128, 0, stream>>>(bsum, nb_scan);
    k_scan_add<<<(N + 255) / 256, 256, 0, stream>>>(hist, incl, bsum, offs, cursor, dinv, N, E);
    k_sortedges<<<(E + 255) / 256, 256, 0, stream>>>(src, dst, dinv, cursor, sedge, E);

    // zero pooled + counts (contiguous)
    k_zero_f<<<(NG * HID + NG + 255) / 256, 256, 0, stream>>>(pooled, NG * HID + NG);

    // 2) layer 1: hw1 = x@W1 ; h1 = relu(gather)
    k_gemm<FEAT><<<2048, 256, 0, stream>>>(x, W1, bufB, N);
    k_gather<<<(N + 3) / 4, 256, 0, stream>>>(bufB, sedge, offs, dinv, b1, bufA, N, 1);

    // 3) layer 2: hw2 = h1@W2 ; agg2 = gather (relu deferred to pool)
    k_gemm<HID><<<2048, 256, 0, stream>>>(bufA, W2, bufB, N);
    k_gather<<<(N + 3) / 4, 256, 0, stream>>>(bufB, sedge, offs, dinv, b2, bufA, N, 0);

    // 4) relu + mean-pool (contiguous ranges, register accumulation)
    {
        const int waves = 2048;
        int rpw = (N + waves - 1) / waves;
        k_relu_pool<<<512, 256, 0, stream>>>(bufA, batch, pooled, counts, N, rpw);
    }
    k_pool_div<<<(NG * HID + 255) / 256, 256, 0, stream>>>(pooled, counts);

    // 5) mu / logvar -> out[900:]
    k_heads<<<(2 * NG * LAT + 255) / 256, 256, 0, stream>>>(pooled, Wmu, bmu, Wlv, blv, out);

    // 6) decoder -> out[0:900]
    k_dec1<<<MAXN, 64, 0, stream>>>(Wl1, bl1, Wl2, bl2, We1, out, dhi, dhj);
    k_dec2<<<1, 256, 0, stream>>>(dhi, dhj, be1, We2, be2, out);
}